// Round 7
// baseline (906.384 us; speedup 1.0000x reference)
//
#include <hip/hip_runtime.h>

// ---------------- types / helpers ----------------
using u16 = unsigned short;
using u32 = unsigned int;
typedef __bf16 bf16x8 __attribute__((ext_vector_type(8)));
typedef u16    u16x8  __attribute__((ext_vector_type(8)));
typedef float  f32x4  __attribute__((ext_vector_type(4)));
typedef float  f32x2  __attribute__((ext_vector_type(2)));
typedef u32    u32x4  __attribute__((ext_vector_type(4)));
typedef u32    u32x2  __attribute__((ext_vector_type(2)));

__device__ __forceinline__ float bf2f(u16 h){ u32 u = ((u32)h)<<16; float f; __builtin_memcpy(&f,&u,4); return f; }
__device__ __forceinline__ u16 f2bf(float f){ u32 u; __builtin_memcpy(&u,&f,4); u32 r = (u + 0x7FFFu + ((u>>16)&1u))>>16; return (u16)r; }
__device__ __forceinline__ float bflo(u32 w){ return bf2f((u16)(w & 0xFFFFu)); }
__device__ __forceinline__ float bfhiw(u32 w){ return bf2f((u16)(w >> 16)); }
__device__ __forceinline__ float sigx(float x){ float e = __expf(-fabsf(x)); float p = 1.f/(1.f+e); return (x>=0.f) ? p : 1.f-p; }

// dtype-dual loads from EXTERNAL buffers (f32 or bf16)
__device__ __forceinline__ float ldsc(const void* p, size_t i, bool f32){
  return f32 ? ((const float*)p)[i] : bf2f(((const u16*)p)[i]);
}
__device__ __forceinline__ u32x4 ld8bf(const void* p, size_t i, bool f32){
  if (!f32) return *(const u32x4*)((const u16*)p + i);
  const f32x4* q = (const f32x4*)((const float*)p + i);
  f32x4 a = q[0], b = q[1];
  u32x4 r;
  r.x = (u32)f2bf(a.x) | ((u32)f2bf(a.y)<<16);
  r.y = (u32)f2bf(a.z) | ((u32)f2bf(a.w)<<16);
  r.z = (u32)f2bf(b.x) | ((u32)f2bf(b.y)<<16);
  r.w = (u32)f2bf(b.z) | ((u32)f2bf(b.w)<<16);
  return r;
}
__device__ __forceinline__ void ld4w(const void* p, size_t i, bool f32,
                                     float& w0, float& w1, float& w2, float& w3){
  if (f32){ f32x4 v = *(const f32x4*)((const float*)p + i); w0=v.x; w1=v.y; w2=v.z; w3=v.w; }
  else { u32x2 v = *(const u32x2*)((const u16*)p + i); w0=bflo(v.x); w1=bfhiw(v.x); w2=bflo(v.y); w3=bfhiw(v.y); }
}

// B=2, L=4096, DM=1024, H=8, HQK=96, HV=192, KEY=768, VAL=1536, CHUNK=64, NCH=64

// ---------------- runtime dtype probe ----------------
__global__ void detect_kernel(const u16* __restrict__ probe, int* __restrict__ flag){
  int t = threadIdx.x;
  int bad = 0;
  for (int i=t; i<1024; i+=64){
    u16 h = probe[i];
    int e = (h>>7)&0xFF;
    if (e >= 0xC0) bad = 1;
  }
  unsigned long long anyb = __ballot(bad);
  if (t==0) *flag = (anyb != 0ull) ? 1 : 0;
}

// ---------------- weight transpose (out[c][r] = in[r][c]), bf16 out ----------------
__global__ void transpose_any(const void* __restrict__ in, u16* __restrict__ out, int R, int C,
                              const int* __restrict__ flagp){
  const bool f32 = (*flagp != 0);
  __shared__ u16 tile[32][33];
  int t = threadIdx.x;
  int tx = t & 31, ty = t >> 5;
  int c0 = blockIdx.x*32, r0 = blockIdx.y*32;
  #pragma unroll
  for (int j=0;j<4;j++){
    int r = r0 + ty + j*8;
    size_t g = (size_t)r*C + c0 + tx;
    tile[ty+j*8][tx] = f32 ? f2bf(((const float*)in)[g]) : ((const u16*)in)[g];
  }
  __syncthreads();
  #pragma unroll
  for (int j=0;j<4;j++){ int c = c0 + ty + j*8; out[(size_t)c*R + r0 + tx] = tile[tx][ty+j*8]; }
}

// ---------------- bf16 MFMA GEMM: C(MxN) = A(MxK) * Bt(NxK)^T ----------------
__global__ __launch_bounds__(256,2) void gemm_bt(const void* __restrict__ A, const u16* __restrict__ Bt,
                                                 void* __restrict__ C, int M, int N, int K,
                                                 const int* __restrict__ flagp, int a_ext, int c_ext,
                                                 int sanitize){
  __shared__ __align__(16) u16 As[128*32];
  __shared__ __align__(16) u16 Bs[128*32];
  const int fl = *flagp;
  const bool af32 = a_ext && fl;
  const bool cf32 = c_ext && fl;
  const int t = threadIdx.x;
  const int bn = blockIdx.x*128, bm = blockIdx.y*128;
  const int wave = t>>6, lane = t&63, quad = lane>>4, l16 = lane&15;
  const int wm = (wave>>1)*64, wn = (wave&1)*64;
  f32x4 acc[4][4] = {};
  const int row0 = t>>2, kp = (t&3)*8;
  const size_t iA0 = (size_t)(bm+row0)*K + kp;
  const size_t iA1 = iA0 + (size_t)64*K;
  const u16* pB0 = Bt + (size_t)(bn+row0)*K + kp;
  const u16* pB1 = pB0 + (size_t)64*K;
  u32x4 ra0 = ld8bf(A, iA0, af32);
  u32x4 ra1 = ld8bf(A, iA1, af32);
  u32x4 rb0 = *(const u32x4*)pB0;
  u32x4 rb1 = *(const u32x4*)pB1;
  const int nk = K>>5;
  for (int kt=0; kt<nk; ++kt){
    __syncthreads();
    ((u32x4*)As)[t]     = ra0;
    ((u32x4*)As)[t+256] = ra1;
    ((u32x4*)Bs)[t]     = rb0;
    ((u32x4*)Bs)[t+256] = rb1;
    __syncthreads();
    if (kt+1 < nk){
      int o = (kt+1)*32;
      ra0 = ld8bf(A, iA0 + o, af32); ra1 = ld8bf(A, iA1 + o, af32);
      rb0 = *(const u32x4*)(pB0 + o); rb1 = *(const u32x4*)(pB1 + o);
    }
    bf16x8 af[4], bfv[4];
    #pragma unroll
    for (int i=0;i<4;i++){
      af[i]  = *(const bf16x8*)&As[(wm + i*16 + l16)*32 + quad*8];
      bfv[i] = *(const bf16x8*)&Bs[(wn + i*16 + l16)*32 + quad*8];
    }
    #pragma unroll
    for (int i=0;i<4;i++)
      #pragma unroll
      for (int j=0;j<4;j++)
        acc[i][j] = __builtin_amdgcn_mfma_f32_16x16x32_bf16(af[i], bfv[j], acc[i][j], 0,0,0);
  }
  #pragma unroll
  for (int i=0;i<4;i++)
    #pragma unroll
    for (int j=0;j<4;j++)
      #pragma unroll
      for (int r2=0;r2<4;r2++){
        int m = bm + wm + i*16 + quad*4 + r2;
        int n = bn + wn + j*16 + l16;
        float v = acc[i][j][r2];
        if (sanitize && !(v==v && v<1e30f && v>-1e30f)) v = 0.f;
        if (cf32) ((float*)C)[(size_t)m*N + n] = v;
        else      ((u16*)C)[(size_t)m*N + n] = f2bf(v);
      }
}

// ---------------- gk / beta (skinny GEMMs N=8 each + activations) ----------------
__global__ __launch_bounds__(256) void gkbeta_kernel(const void* __restrict__ u, const void* __restrict__ Wgk,
    const void* __restrict__ Wb, const void* __restrict__ b_b, const void* __restrict__ A_log,
    const void* __restrict__ dt_b, float* __restrict__ gk, float* __restrict__ beta,
    const int* __restrict__ flagp){
  const bool f32 = (*flagp != 0);
  const int bl = blockIdx.x;
  const int b = bl>>12, l = bl&4095;
  const int t = threadIdx.x;
  float accg[8] = {0,0,0,0,0,0,0,0};
  float accb[8] = {0,0,0,0,0,0,0,0};
  for (int d=t; d<1024; d+=256){
    float uv = ldsc(u, (size_t)bl*1024 + d, f32);
    u32x4 wg = ld8bf(Wgk, (size_t)d*8, f32);
    u32x4 wb = ld8bf(Wb,  (size_t)d*8, f32);
    accg[0] += uv*bflo(wg.x); accg[1] += uv*bfhiw(wg.x);
    accg[2] += uv*bflo(wg.y); accg[3] += uv*bfhiw(wg.y);
    accg[4] += uv*bflo(wg.z); accg[5] += uv*bfhiw(wg.z);
    accg[6] += uv*bflo(wg.w); accg[7] += uv*bfhiw(wg.w);
    accb[0] += uv*bflo(wb.x); accb[1] += uv*bfhiw(wb.x);
    accb[2] += uv*bflo(wb.y); accb[3] += uv*bfhiw(wb.y);
    accb[4] += uv*bflo(wb.z); accb[5] += uv*bfhiw(wb.z);
    accb[6] += uv*bflo(wb.w); accb[7] += uv*bfhiw(wb.w);
  }
  #pragma unroll
  for (int h=0;h<8;h++){
    #pragma unroll
    for (int off=32; off>=1; off>>=1){
      accg[h] += __shfl_down(accg[h], off);
      accb[h] += __shfl_down(accb[h], off);
    }
  }
  __shared__ float red[4][16];
  int wv = t>>6, lane = t&63;
  if (lane==0){
    #pragma unroll
    for (int h=0;h<8;h++){ red[wv][h]=accg[h]; red[wv][8+h]=accb[h]; }
  }
  __syncthreads();
  if (t<16){
    float s = red[0][t]+red[1][t]+red[2][t]+red[3][t];
    if (t<8){
      int h=t;
      float x = s + ldsc(dt_b, h, f32);
      float sp = (x>20.f) ? x : log1pf(__expf(x));
      gk[(size_t)(b*8+h)*4096 + l] = -__expf(ldsc(A_log, h, f32)) * sp;
    } else {
      int h=t-8;
      float x = s + ldsc(b_b, h, f32);
      beta[(size_t)(b*8+h)*4096 + l] = sigx(x);
    }
  }
}

// ---------------- per-chunk cumsum of gk ----------------
__global__ void dec_kernel(const float* __restrict__ gk, float* __restrict__ dec){
  int bhn = blockIdx.x; int i = threadIdx.x;
  float v = gk[(size_t)bhn*64 + i];
  #pragma unroll
  for (int off=1; off<64; off<<=1){
    float x = __shfl_up(v, off);
    if (i >= off) v += x;
  }
  dec[(size_t)bhn*64 + i] = v;
}

// ---------------- conv + silu + per-head L2 norm (q / k) ----------------
__global__ __launch_bounds__(256) void convqk_kernel(const u16* __restrict__ raw, const void* __restrict__ cw,
                                                     u16* __restrict__ outH, float scale,
                                                     const int* __restrict__ flagp){
  const bool f32 = (*flagp != 0);
  const int bl = blockIdx.x; const int b = bl>>12, l = bl&4095;
  const int t = threadIdx.x;
  __shared__ float s[768];
  __shared__ float nrm[8];
  for (int c=t; c<768; c+=256){
    float w0,w1,w2,w3; ld4w(cw, (size_t)c*4, f32, w0,w1,w2,w3);
    float acc = 0.f;
    int base = b*4096;
    if (l>=3) acc += bf2f(raw[(size_t)(base+l-3)*768 + c])*w0;
    if (l>=2) acc += bf2f(raw[(size_t)(base+l-2)*768 + c])*w1;
    if (l>=1) acc += bf2f(raw[(size_t)(base+l-1)*768 + c])*w2;
    acc += bf2f(raw[(size_t)(base+l)*768 + c])*w3;
    s[c] = acc*sigx(acc);
  }
  __syncthreads();
  int h = t>>5, l32 = t&31;
  float p = 0.f;
  for (int i=l32; i<96; i+=32){ float x = s[h*96+i]; p += x*x; }
  p += __shfl_down(p,16,32); p += __shfl_down(p,8,32); p += __shfl_down(p,4,32);
  p += __shfl_down(p,2,32);  p += __shfl_down(p,1,32);
  if (l32==0) nrm[h] = fmaxf(sqrtf(p), 1e-12f);
  __syncthreads();
  for (int c=t; c<768; c+=256){
    int hh = c/96; int d = c - hh*96;
    float v = s[c]/nrm[hh]*scale;
    outH[((size_t)(b*8+hh)*4096 + l)*96 + d] = f2bf(v);
  }
}

// ---------------- conv + silu + *beta (v) ----------------
__global__ __launch_bounds__(256) void convv_kernel(const u16* __restrict__ raw, const void* __restrict__ cw,
                                                    const float* __restrict__ beta, u16* __restrict__ vbH,
                                                    const int* __restrict__ flagp){
  const bool f32 = (*flagp != 0);
  const int bl = blockIdx.x; const int b = bl>>12, l = bl&4095;
  const int t = threadIdx.x;
  for (int c=t; c<1536; c+=256){
    float w0,w1,w2,w3; ld4w(cw, (size_t)c*4, f32, w0,w1,w2,w3);
    float acc = 0.f;
    int base = b*4096;
    if (l>=3) acc += bf2f(raw[(size_t)(base+l-3)*1536 + c])*w0;
    if (l>=2) acc += bf2f(raw[(size_t)(base+l-2)*1536 + c])*w1;
    if (l>=1) acc += bf2f(raw[(size_t)(base+l-1)*1536 + c])*w2;
    acc += bf2f(raw[(size_t)(base+l)*1536 + c])*w3;
    int h = c/192; int d = c - h*192;
    float bv = beta[(size_t)(b*8+h)*4096 + l];
    vbH[((size_t)(b*8+h)*4096 + l)*192 + d] = f2bf(acc*sigx(acc)*bv);
  }
}

// ---------------- chunkprep v3: MFMA products + register substitution + in-place kwT ----------------
// Writes kwT[d][row] = k[row][d]*exp(dl - dec[row]) transposed IN PLACE over kn's chunk
// footprint (kn fully staged to LDS first; no other block reads this range).
__global__ __launch_bounds__(256,2) void chunkprep_kernel(
    const u16* __restrict__ qn, u16* __restrict__ kn, const u16* __restrict__ vb,
    const float* __restrict__ beta, const float* __restrict__ dec,
    u16* __restrict__ attn, u16* __restrict__ kcd, u16* __restrict__ uA){
  __shared__ __align__(16) u16 kS[64*104];
  __shared__ __align__(16) u16 qS[64*104];
  __shared__ float M1[64*64];
  __shared__ float M2[64*64];
  __shared__ float bS[64], dS[64], wf[64];
  const int t = threadIdx.x;
  const int bhn = blockIdx.x;
  const size_t rowb = (size_t)bhn*64;
  const int w = t>>6, l = t&63, l16 = l&15, quad = l>>4;

  // ---- stage k, q (u32x4), dec/beta/wf ----
  #pragma unroll
  for (int j=0;j<3;j++){
    int v = t + 256*j;
    int rr = v/12, c8 = v - rr*12;
    size_t g = (rowb+rr)*96 + c8*8;
    *(u32x4*)&kS[rr*104 + c8*8] = *(const u32x4*)(kn + g);
    *(u32x4*)&qS[rr*104 + c8*8] = *(const u32x4*)(qn + g);
  }
  if (t<64){
    float dv = dec[rowb+t];
    float dl = dec[rowb+63];
    bS[t] = beta[rowb+t]; dS[t] = dv;
    wf[t] = __expf(dl - dv);
  }
  __syncthreads();

  // ---- in-place kwT store (coalesced u32; kn[chunk] already in LDS) ----
  {
    u32* kwT = (u32*)(kn + rowb*96);
    #pragma unroll
    for (int j=0;j<12;j++){
      int idx = t + 256*j;          // 0..3071 = d*32 + row-pair
      int d = idx>>5, rp = idx&31;
      int r0 = rp*2;
      float kw0 = bf2f(kS[r0*104+d])     * wf[r0];
      float kw1 = bf2f(kS[(r0+1)*104+d]) * wf[r0+1];
      kwT[idx] = (u32)f2bf(kw0) | ((u32)f2bf(kw1)<<16);
    }
  }

  // ---- preload RHS column into registers ----
  float x[64];
  const int mode0 = (t<192) ? 0 : 1;
  const int c0 = (t<192) ? t : (t-192);
  if (mode0==0){
    #pragma unroll
    for (int i=0;i<64;i++) x[i] = bf2f(vb[(rowb+i)*192 + c0]);
  } else {
    #pragma unroll
    for (int i=0;i<64;i++) x[i] = bS[i]*bf2f(kS[i*104 + c0]);
  }

  // ---- phase A: QK = q@k^T, KK = k@k^T via MFMA; write attn + M1/M2 ----
  {
    bf16x8 qA[3], kA[3];
    #pragma unroll
    for (int ks=0;ks<3;ks++){
      qA[ks] = *(const bf16x8*)&qS[(w*16+l16)*104 + ks*32 + quad*8];
      kA[ks] = *(const bf16x8*)&kS[(w*16+l16)*104 + ks*32 + quad*8];
    }
    const size_t ab = (size_t)bhn*4096;
    #pragma unroll
    for (int nt=0;nt<4;nt++){
      f32x4 aQ = {0.f,0.f,0.f,0.f}, aK = {0.f,0.f,0.f,0.f};
      #pragma unroll
      for (int ks=0;ks<3;ks++){
        bf16x8 Bf = *(const bf16x8*)&kS[(nt*16+l16)*104 + ks*32 + quad*8];
        aQ = __builtin_amdgcn_mfma_f32_16x16x32_bf16(qA[ks], Bf, aQ,0,0,0);
        aK = __builtin_amdgcn_mfma_f32_16x16x32_bf16(kA[ks], Bf, aK,0,0,0);
      }
      #pragma unroll
      for (int r=0;r<4;r++){
        int row = w*16 + quad*4 + r;
        int col = nt*16 + l16;
        float lm = __expf(fminf(dS[row]-dS[col], 0.f));
        attn[ab + row*64 + col] = (col<=row) ? f2bf(aQ[r]*lm) : (u16)0;
        if (col<row){
          float kkb = aK[r]*bS[row];
          M2[row*64+col] = kkb;
          M1[row*64+col] = kkb*lm;
        }
      }
    }
  }
  __syncthreads();

  // ---- substitution slot 0 ----
  {
    const float* Mb = (mode0==0) ? M1 : M2;
    #pragma unroll
    for (int i=1;i<64;i++){
      float acc = x[i];
      #pragma unroll
      for (int m=0;m<i;m++) acc -= Mb[i*64+m]*x[m];
      x[i] = acc;
    }
    if (mode0==0){
      #pragma unroll
      for (int i=0;i<64;i++) uA[(rowb+i)*192 + c0] = f2bf(x[i]);
    } else {
      #pragma unroll
      for (int i=0;i<64;i++) kcd[(rowb+i)*96 + c0] = f2bf(x[i]);
    }
  }
  // ---- substitution slot 1: kcd cols 64..95 (threads 0..31) ----
  if (t<32){
    const int c1 = 64 + t;
    #pragma unroll
    for (int i=0;i<64;i++) x[i] = bS[i]*bf2f(kS[i*104 + c1]);
    #pragma unroll
    for (int i=1;i<64;i++){
      float acc = x[i];
      #pragma unroll
      for (int m=0;m<i;m++) acc -= M2[i*64+m]*x[m];
      x[i] = acc;
    }
    #pragma unroll
    for (int i=0;i<64;i++) kcd[(rowb+i)*96 + c1] = f2bf(x[i]);
  }
}

// ---------------- sequential chunk scan v4: thin MFMA blocks, kwT from global ----------------
// grid (12,16): 12 col-groups of 16 x 16 (b,h). 256 threads = 4 waves (wave = 16-row M-tile).
__global__ __launch_bounds__(256,2) void scan_kernel(
    const u16* __restrict__ qn, const u16* __restrict__ kwT, const u16* __restrict__ kcd,
    const u16* __restrict__ attn, const u16* __restrict__ uA,
    const float* __restrict__ dec, u16* __restrict__ o){
  __shared__ __align__(16) u16 vnewT[16*72];    // vnew^T [col][row]
  __shared__ __align__(16) u16 Sbf[16*104];     // S^T bf16 [col][d]
  __shared__ float edS[2][64];
  __shared__ float expdlS[2];
  const int t = threadIdx.x;
  const int eg = blockIdx.x;    // 0..11
  const int bh = blockIdx.y;    // 0..15
  const int e0 = eg*16;
  const int w = t>>6, l = t&63, l16 = l&15, quad = l>>4;
  // pass2b product assignment: wave0: mt{0,1}, wave1: mt{2,3}, wave2: {4}, wave3: {5}
  const int nprod = (w<2)?2:1;
  const int mt0 = (w<2)? w*2 : (w+2);

  for (int i=t; i<16*104; i+=256) Sbf[i] = 0;
  size_t rowb = (size_t)bh*4096;
  size_t ab   = (size_t)bh*64*4096;

  u32x4 qF[3], kcdF[3], attF[2], kwF[2][2];
  u16 uFv[4];
  auto pfQKU = [&](size_t rb){
    #pragma unroll
    for (int ks=0; ks<3; ks++){
      size_t g = (rb + w*16 + l16)*96 + ks*32 + quad*8;
      qF[ks]   = *(const u32x4*)(qn + g);
      kcdF[ks] = *(const u32x4*)(kcd + g);
    }
    #pragma unroll
    for (int r=0;r<4;r++)
      uFv[r] = uA[(rb + w*16 + quad*4 + r)*192 + e0 + l16];
  };
  auto pfKW = [&](size_t rb){
    #pragma unroll
    for (int p=0;p<2;p++)
      if (p < nprod){
        int mt = mt0 + p;
        #pragma unroll
        for (int ks=0;ks<2;ks++)
          kwF[p][ks] = *(const u32x4*)(kwT + rb*96 + (mt*16+l16)*64 + ks*32 + quad*8);
      }
  };
  auto pfATT = [&](size_t abN){
    #pragma unroll
    for (int ks=0; ks<2; ks++)
      attF[ks] = *(const u32x4*)(attn + abN + (w*16 + l16)*64 + ks*32 + quad*8);
  };
  auto pfDEC = [&](size_t rb, int nb){
    if (t<64){
      float dv = dec[rb + t];
      float dl = __shfl(dv, 63);
      edS[nb][t] = __expf(dv);
      if (t==0) expdlS[nb] = __expf(dl);
    }
  };

  pfQKU(rowb); pfKW(rowb); pfATT(ab); pfDEC(rowb, 0);
  f32x4 Sreg[2] = {};
  __syncthreads();

  for (int n=0;n<64;n++){
    const int b = n&1, nb = b^1;
    const size_t rowbN = rowb + 64;
    const size_t abN = ab + 4096;
    // ---- pass 1: T1 = kcd@S, T2 = q@S (single 16-col tile) ----
    f32x4 accA = {0.f,0.f,0.f,0.f}, accQ = {0.f,0.f,0.f,0.f};
    #pragma unroll
    for (int ks=0;ks<3;ks++){
      bf16x8 Bf = *(const bf16x8*)&Sbf[l16*104 + ks*32 + quad*8];
      accA = __builtin_amdgcn_mfma_f32_16x16x32_bf16(*(const bf16x8*)&kcdF[ks], Bf, accA,0,0,0);
      accQ = __builtin_amdgcn_mfma_f32_16x16x32_bf16(*(const bf16x8*)&qF[ks],  Bf, accQ,0,0,0);
    }
    #pragma unroll
    for (int r=0;r<4;r++){
      float ed = edS[b][w*16 + quad*4 + r];
      float vn = bf2f(uFv[r]) - ed*accA[r];
      vnewT[l16*72 + (w*16+quad*4+r)] = f2bf(vn);
      accQ[r] *= ed;
    }
    // ---- prefetch chunk n+1 (q,kcd,u,dec — not kw/att yet, still in use) ----
    if (n<63){ pfQKU(rowbN); pfDEC(rowbN, nb); }
    __syncthreads();   // vnewT ready; Sbf pass-1 reads done
    // ---- pass 2a: o = ed*q@S + attn@vnew ----
    #pragma unroll
    for (int ks=0;ks<2;ks++){
      bf16x8 Bv = *(const bf16x8*)&vnewT[l16*72 + ks*32 + quad*8];
      accQ = __builtin_amdgcn_mfma_f32_16x16x32_bf16(*(const bf16x8*)&attF[ks], Bv, accQ,0,0,0);
    }
    #pragma unroll
    for (int r=0;r<4;r++)
      o[(rowb + w*16 + quad*4 + r)*192 + e0 + l16] = f2bf(accQ[r]);
    if (n<63) pfATT(abN);
    // ---- pass 2b: S = exp(dl)*S + kwT @ vnew ----
    const float aexp = expdlS[b];
    #pragma unroll
    for (int p=0;p<2;p++){
      if (p < nprod){
        f32x4 acc = {0.f,0.f,0.f,0.f};
        #pragma unroll
        for (int ks=0;ks<2;ks++){
          bf16x8 Bv = *(const bf16x8*)&vnewT[l16*72 + ks*32 + quad*8];
          acc = __builtin_amdgcn_mfma_f32_16x16x32_bf16(*(const bf16x8*)&kwF[p][ks], Bv, acc,0,0,0);
        }
        f32x4 ns;
        ns.x = Sreg[p].x*aexp + acc.x;
        ns.y = Sreg[p].y*aexp + acc.y;
        ns.z = Sreg[p].z*aexp + acc.z;
        ns.w = Sreg[p].w*aexp + acc.w;
        Sreg[p] = ns;
        int mt = mt0 + p;
        u32x2 pv;
        pv.x = (u32)f2bf(ns.x) | ((u32)f2bf(ns.y)<<16);
        pv.y = (u32)f2bf(ns.z) | ((u32)f2bf(ns.w)<<16);
        *(u32x2*)&Sbf[l16*104 + mt*16 + quad*4] = pv;
      }
    }
    if (n<63) pfKW(rowbN);   // kwF consumed; refetch for next chunk
    __syncthreads();
    rowb = rowbN; ab = abN;
  }
}

// ---------------- gated RMSNorm epilogue ----------------
__global__ __launch_bounds__(192) void epilogue_kernel(const u16* __restrict__ o, const u16* __restrict__ glin,
                                                       const void* __restrict__ nw, u16* __restrict__ on,
                                                       const int* __restrict__ flagp){
  const bool f32 = (*flagp != 0);
  const int bl = blockIdx.x; const int h = blockIdx.y; const int d = threadIdx.x;
  const int b = bl>>12, l = bl&4095;
  float x = bf2f(o[((size_t)(b*8+h)*4096 + l)*192 + d]);
  float p = x*x;
  p += __shfl_down(p,32); p += __shfl_down(p,16); p += __shfl_down(p,8);
  p += __shfl_down(p,4);  p += __shfl_down(p,2);  p += __shfl_down(p,1);
  __shared__ float red[3];
  int wv = d>>6;
  if ((d&63)==0) red[wv] = p;
  __syncthreads();
  float ss = red[0]+red[1]+red[2];
  float rs = rsqrtf(ss/192.f + 1e-5f);
  float g = bf2f(glin[(size_t)bl*1536 + h*192 + d]);
  float val = x*rs*ldsc(nw, d, f32) * g*sigx(g);
  on[(size_t)bl*1536 + h*192 + d] = f2bf(val);
}

// ---------------- launch ----------------
extern "C" void kernel_launch(void* const* d_in, const int* in_sizes, int n_in,
                              void* d_out, int out_size, void* d_ws, size_t ws_size,
                              hipStream_t stream){
  (void)in_sizes; (void)n_in; (void)out_size; (void)ws_size;
  const void* u     = d_in[0];
  const void* Wq    = d_in[1];
  const void* Wk    = d_in[2];
  const void* Wv    = d_in[3];
  const void* Wg    = d_in[4];
  const void* Wo    = d_in[5];
  const void* Wgk   = d_in[6];
  const void* Wb    = d_in[7];
  const void* b_b   = d_in[8];
  const void* A_log = d_in[9];
  const void* dt_b  = d_in[10];
  const void* cq    = d_in[11];
  const void* ck    = d_in[12];
  const void* cv    = d_in[13];
  const void* nw    = d_in[14];

  char* w = (char*)d_ws;
  size_t off = 0;
  auto take = [&](size_t bytes)->char*{
    char* p = w + off;
    off += (bytes + 255) & ~(size_t)255;
    return p;
  };
  int* flag = (int*)take(256);
  u16* WqT  = (u16*)take((size_t)768*1024*2);
  u16* WkT  = (u16*)take((size_t)768*1024*2);
  u16* WvT  = (u16*)take((size_t)1536*1024*2);
  u16* WgT  = (u16*)take((size_t)1536*1024*2);
  u16* WoT  = (u16*)take((size_t)1024*1536*2);
  u16* qraw = (u16*)take((size_t)8192*768*2);
  u16* kraw = (u16*)take((size_t)8192*768*2);
  u16* vraw = (u16*)take((size_t)8192*1536*2);
  u16* qn   = (u16*)take((size_t)8192*768*2);
  u16* kn   = (u16*)take((size_t)8192*768*2);   // becomes kwT (in place) after chunkprep
  u16* vb   = (u16*)take((size_t)8192*1536*2);
  float* gkA   = (float*)WqT;
  float* betaA = gkA + 65536;
  float* decA  = betaA + 65536;
  u16* attnA = qraw;
  u16* kcdA  = kraw;
  u16* uuA   = vraw;
  u16* glinA = qn;
  u16* oA    = vb;
  u16* onA   = vraw;

  detect_kernel<<<1,64,0,stream>>>((const u16*)u, flag);
  transpose_any<<<dim3(768/32, 1024/32),256,0,stream>>>(Wq, WqT, 1024, 768, flag);
  transpose_any<<<dim3(768/32, 1024/32),256,0,stream>>>(Wk, WkT, 1024, 768, flag);
  transpose_any<<<dim3(1536/32,1024/32),256,0,stream>>>(Wv, WvT, 1024, 1536, flag);
  transpose_any<<<dim3(1536/32,1024/32),256,0,stream>>>(Wg, WgT, 1024, 1536, flag);
  transpose_any<<<dim3(1024/32,1536/32),256,0,stream>>>(Wo, WoT, 1536, 1024, flag);
  gemm_bt<<<dim3(6,64),256,0,stream>>>(u, WqT, qraw, 8192, 768, 1024, flag, 1, 0, 0);
  gemm_bt<<<dim3(6,64),256,0,stream>>>(u, WkT, kraw, 8192, 768, 1024, flag, 1, 0, 0);
  gemm_bt<<<dim3(12,64),256,0,stream>>>(u, WvT, vraw, 8192, 1536, 1024, flag, 1, 0, 0);
  gkbeta_kernel<<<8192,256,0,stream>>>(u, Wgk, Wb, b_b, A_log, dt_b, gkA, betaA, flag);
  dec_kernel<<<1024,64,0,stream>>>(gkA, decA);
  convqk_kernel<<<8192,256,0,stream>>>(qraw, cq, qn, 0.10206207261596575f, flag);
  convqk_kernel<<<8192,256,0,stream>>>(kraw, ck, kn, 1.0f, flag);
  convv_kernel<<<8192,256,0,stream>>>(vraw, cv, betaA, vb, flag);
  chunkprep_kernel<<<1024,256,0,stream>>>(qn, kn, vb, betaA, decA, attnA, kcdA, uuA);
  scan_kernel<<<dim3(12,16),256,0,stream>>>(qn, kn, kcdA, attnA, uuA, decA, oA);
  gemm_bt<<<dim3(12,64),256,0,stream>>>(u, WgT, glinA, 8192, 1536, 1024, flag, 1, 0, 0);
  epilogue_kernel<<<dim3(8192,8),192,0,stream>>>(oA, glinA, nw, onA, flag);
  gemm_bt<<<dim3(8,64),256,0,stream>>>(onA, WoT, d_out, 8192, 1024, 1536, flag, 0, 1, 1);
}